// Round 3
// baseline (1749.169 us; speedup 1.0000x reference)
//
#include <hip/hip_runtime.h>
#include <math.h>

#define LN_ 256      // ligand count L
#define PN_ 1024     // protein count P
#define DN_ 256      // model dim D
#define NH_ 4
#define RBF_N 50
#define NL_ 2
#define HD_ 64
#define EPSV 1e-5f

__device__ __forceinline__ float fast_sigmoid(float x){ return 1.f/(1.f+__expf(-x)); }
__device__ __forceinline__ float fast_silu(float x){ return x/(1.f+__expf(-x)); }

// ---------------------------------------------------------------------------
// gemm8: C[row,n] = act( dot(A[row,:K], W[:,n]) + b[n] ), 8 rows per block,
// up to 3 segments per launch (block ranges). 256 threads == output cols.
// transOut: write C[n*PN_ + row] (used to produce K^T).
// ---------------------------------------------------------------------------
struct GSeg {
  const float* A; const float* W; const float* bias; float* C;
  int K; int act; int transOut;
};
struct GArgs { GSeg s[3]; int b0, b1; };

__global__ __launch_bounds__(256) void gemm8(GArgs ga)
{
  extern __shared__ float sA[];   // 8 * K floats
  int bid = blockIdx.x;
  int si = (bid < ga.b0) ? 0 : (bid < ga.b1 ? 1 : 2);
  int base = (si == 0) ? 0 : ((si == 1) ? ga.b0 : ga.b1);
  GSeg sg = ga.s[si];
  int row0 = (bid - base) * 8;
  int K = sg.K;
  int t = threadIdx.x;
  for (int idx = t; idx < 8 * K; idx += 256) {
    int r = idx / K, k = idx - r * K;
    sA[idx] = sg.A[(size_t)(row0 + r) * K + k];
  }
  __syncthreads();
  float acc[8];
  float bv = sg.bias ? sg.bias[t] : 0.f;
  #pragma unroll
  for (int r = 0; r < 8; r++) acc[r] = bv;
  for (int k = 0; k < K; k++) {
    float w = sg.W[(size_t)k * DN_ + t];
    #pragma unroll
    for (int r = 0; r < 8; r++) acc[r] = fmaf(sA[r * K + k], w, acc[r]);
  }
  #pragma unroll
  for (int r = 0; r < 8; r++) {
    float v = acc[r];
    if (sg.act == 1) v = fast_silu(v);
    if (sg.transOut) sg.C[(size_t)t * PN_ + row0 + r] = v;
    else             sg.C[(size_t)(row0 + r) * DN_ + t] = v;
  }
}

// ---------------------------------------------------------------------------
// scores + rbf bias + softmax over P, all 4 heads per block. grid = L blocks.
// Kt is K transposed: [DN_][PN_]. attn layout [l][h][p].
// amean (nullable): attn_out[l*P+p] = mean_h attn
// ---------------------------------------------------------------------------
__global__ __launch_bounds__(256) void scores_softmax_l(
    const float* __restrict__ Q, const float* __restrict__ Kt,
    const float* __restrict__ rbf, const float* __restrict__ rw,
    const float* __restrict__ rb, float* __restrict__ attn,
    float* __restrict__ amean)
{
  int l = blockIdx.x, t = threadIdx.x, lane = t & 63, wv = t >> 6;
  __shared__ float qs[DN_];
  __shared__ float rws[NH_][RBF_N];
  __shared__ float redm[16], reds[16];
  qs[t] = Q[(size_t)l * DN_ + t];
  if (t < RBF_N * NH_) rws[t & 3][t >> 2] = rw[t];   // rw[k*NH+h]
  __syncthreads();

  float sc[NH_][4];
  for (int i = 0; i < 4; i++) {
    int p = t + (i << 8);
    // rbf row: 200B stride -> 8-byte aligned, float2 safe
    const float2* rr2 = (const float2*)(rbf + ((size_t)(l << 10) + p) * RBF_N);
    float s2[NH_] = {0.f, 0.f, 0.f, 0.f};
    #pragma unroll
    for (int k2 = 0; k2 < RBF_N / 2; k2++) {
      float2 rv = rr2[k2];
      int k = 2 * k2;
      s2[0] = fmaf(rv.x, rws[0][k], fmaf(rv.y, rws[0][k + 1], s2[0]));
      s2[1] = fmaf(rv.x, rws[1][k], fmaf(rv.y, rws[1][k + 1], s2[1]));
      s2[2] = fmaf(rv.x, rws[2][k], fmaf(rv.y, rws[2][k + 1], s2[2]));
      s2[3] = fmaf(rv.x, rws[3][k], fmaf(rv.y, rws[3][k + 1], s2[3]));
    }
    #pragma unroll
    for (int h = 0; h < NH_; h++) {
      const float* kp = Kt + ((size_t)(h << 6) << 10) + p;
      float a = 0.f;
      #pragma unroll 8
      for (int d = 0; d < HD_; d++) a = fmaf(qs[(h << 6) + d], kp[(size_t)d << 10], a);
      sc[h][i] = a * 0.125f + s2[h] + rb[h];
    }
  }

  // per-head max over all 1024 p
  float mh[NH_];
  #pragma unroll
  for (int h = 0; h < NH_; h++) {
    float m = fmaxf(fmaxf(sc[h][0], sc[h][1]), fmaxf(sc[h][2], sc[h][3]));
    for (int o = 32; o > 0; o >>= 1) m = fmaxf(m, __shfl_xor(m, o));
    if (lane == 0) redm[h * 4 + wv] = m;
  }
  __syncthreads();
  #pragma unroll
  for (int h = 0; h < NH_; h++)
    mh[h] = fmaxf(fmaxf(redm[h * 4 + 0], redm[h * 4 + 1]),
                  fmaxf(redm[h * 4 + 2], redm[h * 4 + 3]));

  float e[NH_][4], inv[NH_];
  #pragma unroll
  for (int h = 0; h < NH_; h++) {
    float s = 0.f;
    #pragma unroll
    for (int i = 0; i < 4; i++) { e[h][i] = __expf(sc[h][i] - mh[h]); s += e[h][i]; }
    for (int o = 32; o > 0; o >>= 1) s += __shfl_xor(s, o);
    if (lane == 0) reds[h * 4 + wv] = s;
  }
  __syncthreads();
  #pragma unroll
  for (int h = 0; h < NH_; h++)
    inv[h] = 1.f / (reds[h * 4 + 0] + reds[h * 4 + 1] + reds[h * 4 + 2] + reds[h * 4 + 3]);

  #pragma unroll
  for (int h = 0; h < NH_; h++)
    for (int i = 0; i < 4; i++)
      attn[(((size_t)(l << 2) + h) << 10) + t + (i << 8)] = e[h][i] * inv[h];

  if (amean) {
    for (int i = 0; i < 4; i++) {
      float s = e[0][i] * inv[0] + e[1][i] * inv[1] + e[2][i] * inv[2] + e[3][i] * inv[3];
      amean[((size_t)l << 10) + t + (i << 8)] = s * 0.25f;
    }
  }
}

// ---------------------------------------------------------------------------
// attend + output proj + residual + layernorm, fused. grid = L blocks.
// ---------------------------------------------------------------------------
__global__ __launch_bounds__(256) void attend_proj_ln(
    const float* __restrict__ attn, const float* __restrict__ V,
    const float* __restrict__ ow, const float* __restrict__ ob,
    const float* __restrict__ g, const float* __restrict__ bb,
    float* __restrict__ lig)
{
  int l = blockIdx.x, t = threadIdx.x, lane = t & 63, wv = t >> 6;
  int h = t >> 6, d = t & 63;
  __shared__ float as[DN_];
  __shared__ float red[8];
  const float* aw = attn + (((size_t)(l << 2) + h) << 10);
  const float* Vp = V + (h << 6) + d;
  float acc = 0.f;
  #pragma unroll 8
  for (int p = 0; p < PN_; p++) acc = fmaf(aw[p], Vp[(size_t)p << 8], acc);
  as[t] = acc;
  __syncthreads();
  float acc2 = ob[t];
  #pragma unroll 4
  for (int k = 0; k < DN_; k++) acc2 = fmaf(as[k], ow[(size_t)(k << 8) + t], acc2);
  float x = lig[((size_t)l << 8) + t] + acc2;
  float sm = x;
  for (int o = 32; o > 0; o >>= 1) sm += __shfl_xor(sm, o);
  if (lane == 0) red[wv] = sm;
  __syncthreads();
  float mu = (red[0] + red[1] + red[2] + red[3]) * (1.f / DN_);
  float dx = x - mu;
  float v = dx * dx;
  for (int o = 32; o > 0; o >>= 1) v += __shfl_xor(v, o);
  if (lane == 0) red[4 + wv] = v;
  __syncthreads();
  float var = (red[4] + red[5] + red[6] + red[7]) * (1.f / DN_);
  lig[((size_t)l << 8) + t] = dx * (1.f / sqrtf(var + EPSV)) * g[t] + bb[t];
}

// ---------------------------------------------------------------------------
// gate logits.  grid = L blocks, 128 threads.
// ---------------------------------------------------------------------------
__global__ __launch_bounds__(128) void gate_logits_k(
    const float* __restrict__ lig, const float* __restrict__ w1,
    const float* __restrict__ b1, const float* __restrict__ w2,
    const float* __restrict__ b2, float* __restrict__ glog)
{
  int l = blockIdx.x, n = threadIdx.x, lane = n & 63, wv = n >> 6;
  __shared__ float ls[DN_];
  __shared__ float red[2];
  ls[n] = lig[(size_t)l * DN_ + n];
  ls[n + 128] = lig[(size_t)l * DN_ + n + 128];
  __syncthreads();
  float acc = b1[n];
  #pragma unroll 4
  for (int k = 0; k < DN_; k++) acc = fmaf(ls[k], w1[k * 128 + n], acc);
  float part = tanhf(acc) * w2[n];
  for (int o = 32; o > 0; o >>= 1) part += __shfl_xor(part, o);
  if (lane == 0) red[wv] = part;
  __syncthreads();
  if (n == 0) glog[l] = red[0] + red[1] + b2[0];
}

// ---------------------------------------------------------------------------
// gate softmax + pooled repr + both heads. 1 block, 256 threads.
// ---------------------------------------------------------------------------
__global__ __launch_bounds__(256) void pool_heads(
    const float* __restrict__ lig, const float* __restrict__ glog,
    const float* __restrict__ afw1, const float* __restrict__ afb1,
    const float* __restrict__ afw2, const float* __restrict__ afb2,
    const float* __restrict__ cfw1, const float* __restrict__ cfb1,
    const float* __restrict__ cfw2, const float* __restrict__ cfb2,
    float* __restrict__ out)
{
  __shared__ float wsh[LN_];
  __shared__ float cr[DN_];
  __shared__ float h1s[DN_];
  __shared__ float h2s[128];
  __shared__ float red[8];
  int t = threadIdx.x, lane = t & 63, wv = t >> 6;
  float x = glog[t];
  float m = x;
  for (int o = 32; o > 0; o >>= 1) m = fmaxf(m, __shfl_xor(m, o));
  if (lane == 0) red[wv] = m;
  __syncthreads();
  m = fmaxf(fmaxf(red[0], red[1]), fmaxf(red[2], red[3]));
  float e = __expf(x - m);
  float s = e;
  for (int o = 32; o > 0; o >>= 1) s += __shfl_xor(s, o);
  if (lane == 0) red[4 + wv] = s;
  __syncthreads();
  s = red[4] + red[5] + red[6] + red[7];
  wsh[t] = e / s;
  __syncthreads();
  float acc = 0.f;
  #pragma unroll 4
  for (int l2 = 0; l2 < LN_; l2++) acc = fmaf(wsh[l2], lig[(size_t)l2 * DN_ + t], acc);
  cr[t] = acc;
  __syncthreads();
  float a = afb1[t];
  #pragma unroll 4
  for (int d = 0; d < DN_; d++) a = fmaf(cr[d], afw1[d * DN_ + t], a);
  h1s[t] = fast_silu(a);
  if (t < 128) {
    float c = cfb1[t];
    #pragma unroll 4
    for (int d = 0; d < DN_; d++) c = fmaf(cr[d], cfw1[d * 128 + t], c);
    h2s[t] = fast_silu(c);
  }
  __syncthreads();
  float pp = h1s[t] * afw2[t];
  for (int o = 32; o > 0; o >>= 1) pp += __shfl_xor(pp, o);
  if (lane == 0) red[wv] = pp;
  float cp = (t < 128) ? h2s[t] * cfw2[t] : 0.f;
  for (int o = 32; o > 0; o >>= 1) cp += __shfl_xor(cp, o);
  if (lane == 0) red[4 + wv] = cp;
  __syncthreads();
  if (t == 0) {
    float pkd = red[0] + red[1] + red[2] + red[3] + afb2[0];
    float cl  = red[4] + red[5] + red[6] + red[7] + cfb2[0];
    float conf = fast_sigmoid(cl);
    out[0] = pkd * conf;
    out[1] = pkd;
    out[2] = conf;
  }
}

// ---------------------------------------------------------------------------
// fused pair head with LDS-staged B tile.
// imap[l,p,:] = sigmoid( silu(A[l,:]+B[p,:]+rbf[l,p,:]@Wr) @ w2 + ib2 )
// grid = L*P/256 = 1024 blocks (4 blocks per l, 256 p each).
// LDS 36KB caps at 4 blocks/CU; launch_bounds(256,4) = 4 waves/EU matches.
// ---------------------------------------------------------------------------
#define PM_PAD 36   // padded LDS row stride in floats (32 data + 4 pad)
__global__ __launch_bounds__(256, 4) void pair_main(
    const float* __restrict__ A, const float* __restrict__ B,
    const float* __restrict__ rbf, const float* __restrict__ Wr,
    const float* __restrict__ w2, const float* __restrict__ ib2,
    float* __restrict__ imap)
{
  __shared__ float sB[256 * PM_PAD];
  int t = threadIdx.x;
  int bid = blockIdx.x;
  int l = bid >> 2;
  int p0 = (bid & 3) << 8;
  int idx = (l << 10) + p0 + t;

  float r[RBF_N];
  // rbf row: 200B stride -> 8-byte aligned, float2 safe
  const float2* rr2 = (const float2*)(rbf + (size_t)idx * RBF_N);
  #pragma unroll
  for (int k2 = 0; k2 < RBF_N / 2; k2++) {
    float2 v = rr2[k2];
    r[2 * k2] = v.x;
    r[2 * k2 + 1] = v.y;
  }

  const float* Ar = A + (size_t)l * DN_;   // wave-uniform -> s_load
  float acc[5];
  #pragma unroll
  for (int o = 0; o < 5; o++) acc[o] = ib2[o];

  for (int dt = 0; dt < DN_; dt += 32) {
    __syncthreads();
    // stage B[p0..p0+255][dt..dt+31] coalesced (float4)
    #pragma unroll
    for (int j = 0; j < 8; j++) {
      int j4 = t + j * 256;           // 0..2047
      int pp = j4 >> 3, c = j4 & 7;
      float4 bv = *(const float4*)(B + (size_t)(p0 + pp) * DN_ + dt + c * 4);
      *(float4*)(sB + pp * PM_PAD + c * 4) = bv;
    }
    __syncthreads();

    #pragma unroll
    for (int c = 0; c < 8; c++) {
      int d = dt + c * 4;
      float4 b4 = *(const float4*)(sB + t * PM_PAD + c * 4);
      float h0 = Ar[d + 0] + b4.x;
      float h1 = Ar[d + 1] + b4.y;
      float h2 = Ar[d + 2] + b4.z;
      float h3 = Ar[d + 3] + b4.w;
      #pragma unroll
      for (int k = 0; k < RBF_N; k++) {
        float4 w4 = *(const float4*)(Wr + k * DN_ + d);   // uniform -> s_load
        h0 = fmaf(r[k], w4.x, h0);
        h1 = fmaf(r[k], w4.y, h1);
        h2 = fmaf(r[k], w4.z, h2);
        h3 = fmaf(r[k], w4.w, h3);
      }
      float s0 = fast_silu(h0), s1 = fast_silu(h1), s2 = fast_silu(h2), s3 = fast_silu(h3);
      #pragma unroll
      for (int o = 0; o < 5; o++) {
        acc[o] += fmaf(s0, w2[(d + 0) * 5 + o], fmaf(s1, w2[(d + 1) * 5 + o],
                  fmaf(s2, w2[(d + 2) * 5 + o], s3 * w2[(d + 3) * 5 + o])));
      }
    }
  }
  float* op = imap + (size_t)idx * 5;
  #pragma unroll
  for (int o = 0; o < 5; o++) op[o] = fast_sigmoid(acc[o]);
}

// ---------------------------------------------------------------------------
extern "C" void kernel_launch(void* const* d_in, const int* in_sizes, int n_in,
                              void* d_out, int out_size, void* d_ws, size_t ws_size,
                              hipStream_t stream)
{
  const float* pf    = (const float*)d_in[0];
  const float* lf    = (const float*)d_in[1];
  const float* rbf   = (const float*)d_in[4];
  const float* pe_w1 = (const float*)d_in[5];
  const float* pe_b1 = (const float*)d_in[6];
  const float* pe_w2 = (const float*)d_in[7];
  const float* pe_b2 = (const float*)d_in[8];
  const float* le_w1 = (const float*)d_in[9];
  const float* le_b1 = (const float*)d_in[10];
  const float* le_w2 = (const float*)d_in[11];
  const float* le_b2 = (const float*)d_in[12];
  const float* qw = (const float*)d_in[13];
  const float* qb = (const float*)d_in[14];
  const float* kw = (const float*)d_in[15];
  const float* kb = (const float*)d_in[16];
  const float* vw = (const float*)d_in[17];
  const float* vb = (const float*)d_in[18];
  const float* rw = (const float*)d_in[19];
  const float* rb = (const float*)d_in[20];
  const float* ow = (const float*)d_in[21];
  const float* ob = (const float*)d_in[22];
  const float* ln_g = (const float*)d_in[23];
  const float* ln_b = (const float*)d_in[24];
  const float* pg_w1 = (const float*)d_in[25];
  const float* pg_b1 = (const float*)d_in[26];
  const float* pg_w2 = (const float*)d_in[27];
  const float* pg_b2 = (const float*)d_in[28];
  const float* af_w1 = (const float*)d_in[29];
  const float* af_b1 = (const float*)d_in[30];
  const float* af_w2 = (const float*)d_in[31];
  const float* af_b2 = (const float*)d_in[32];
  const float* cf_w1 = (const float*)d_in[33];
  const float* cf_b1 = (const float*)d_in[34];
  const float* cf_w2 = (const float*)d_in[35];
  const float* cf_b2 = (const float*)d_in[36];
  const float* iw1 = (const float*)d_in[37];
  const float* ib1 = (const float*)d_in[38];
  const float* iw2 = (const float*)d_in[39];
  const float* ib2 = (const float*)d_in[40];

  float* out = (float*)d_out;

  // workspace layout (floats)
  float* w = (float*)d_ws;
  size_t off = 0;
  float* prot_h = w + off; off += (size_t)PN_ * DN_;
  float* lig_h  = w + off; off += (size_t)LN_ * DN_;
  float* ph1    = w + off; off += (size_t)PN_ * DN_;
  float* lh1    = w + off; off += (size_t)LN_ * DN_;
  float* Qb     = w + off; off += (size_t)LN_ * DN_;
  float* Kt     = w + off; off += (size_t)DN_ * PN_;   // K transposed [D][P]
  float* Vb     = w + off; off += (size_t)PN_ * DN_;
  float* attn   = w + off; off += (size_t)LN_ * NH_ * PN_;
  float* pairA  = w + off; off += (size_t)LN_ * DN_;
  float* pairB  = w + off; off += (size_t)PN_ * DN_;
  float* glog   = w + off; off += LN_;

  const int PB = PN_ / 8;   // 128 blocks for P-sized matrices
  const int LB = LN_ / 8;   // 32 blocks for L-sized
  const size_t smax = 8 * DN_ * sizeof(float);

  // encoder stage 1: ph1 = silu(pf@pe_w1+pe_b1), lh1 = silu(lf@le_w1+le_b1)
  {
    GArgs ga;
    ga.s[0] = { pf, pe_w1, pe_b1, ph1, 20, 1, 0 };
    ga.s[1] = { lf, le_w1, le_b1, lh1, 20, 1, 0 };
    ga.s[2] = ga.s[1];
    ga.b0 = PB; ga.b1 = PB + LB;
    gemm8<<<PB + LB, 256, smax, stream>>>(ga);
  }
  // encoder stage 2: prot_h = ph1@pe_w2+pe_b2, lig_h = lh1@le_w2+le_b2
  {
    GArgs ga;
    ga.s[0] = { ph1, pe_w2, pe_b2, prot_h, DN_, 0, 0 };
    ga.s[1] = { lh1, le_w2, le_b2, lig_h, DN_, 0, 0 };
    ga.s[2] = ga.s[1];
    ga.b0 = PB; ga.b1 = PB + LB;
    gemm8<<<PB + LB, 256, smax, stream>>>(ga);
  }

  // cross-attention layers
  for (int i = 0; i < NL_; i++) {
    const size_t wo = (size_t)i * DN_ * DN_;
    {
      GArgs ga;
      ga.s[0] = { lig_h,  qw + wo, qb + i * DN_, Qb, DN_, 0, 0 };
      ga.s[1] = { prot_h, kw + wo, kb + i * DN_, Kt, DN_, 0, 1 };  // K^T
      ga.s[2] = { prot_h, vw + wo, vb + i * DN_, Vb, DN_, 0, 0 };
      ga.b0 = LB; ga.b1 = LB + PB;
      gemm8<<<LB + 2 * PB, 256, smax, stream>>>(ga);
    }
    scores_softmax_l<<<LN_, 256, 0, stream>>>(
        Qb, Kt, rbf, rw + (size_t)i * RBF_N * NH_, rb + i * NH_, attn,
        (i == NL_ - 1) ? (out + 3 + (size_t)LN_ * PN_ * 5) : nullptr);
    attend_proj_ln<<<LN_, 256, 0, stream>>>(attn, Vb, ow + wo, ob + i * DN_,
                                            ln_g + i * DN_, ln_b + i * DN_, lig_h);
  }

  // gated pooling + heads
  gate_logits_k<<<LN_, 128, 0, stream>>>(lig_h, pg_w1, pg_b1, pg_w2, pg_b2, glog);
  pool_heads<<<1, 256, 0, stream>>>(lig_h, glog, af_w1, af_b1, af_w2, af_b2,
                                    cf_w1, cf_b1, cf_w2, cf_b2, out);

  // pair head precompute: pairA = lig_h@iw1[0:256]+ib1, pairB = prot_h@iw1[256:512]
  {
    GArgs ga;
    ga.s[0] = { lig_h,  iw1,                       ib1,     pairA, DN_, 0, 0 };
    ga.s[1] = { prot_h, iw1 + (size_t)DN_ * DN_,   nullptr, pairB, DN_, 0, 0 };
    ga.s[2] = ga.s[1];
    ga.b0 = LB; ga.b1 = LB + PB;
    gemm8<<<LB + PB, 256, smax, stream>>>(ga);
  }

  // fused pair head
  pair_main<<<(LN_ * PN_) / 256, 256, 0, stream>>>(
      pairA, pairB, rbf, iw1 + (size_t)2 * DN_ * DN_, iw2, ib2, out + 3);
}

// Round 4
// 732.673 us; speedup vs baseline: 2.3874x; 2.3874x over previous
//
#include <hip/hip_runtime.h>
#include <math.h>

#define LN_ 256      // ligand count L
#define PN_ 1024     // protein count P
#define DN_ 256      // model dim D
#define NH_ 4
#define RBF_N 50
#define NL_ 2
#define HD_ 64
#define EPSV 1e-5f
#define LP_ (LN_ * PN_)

__device__ __forceinline__ float fast_sigmoid(float x){ return 1.f/(1.f+__expf(-x)); }
__device__ __forceinline__ float fast_silu(float x){ return x/(1.f+__expf(-x)); }

// ---------------------------------------------------------------------------
// gemm8: C[row,n] = act( dot(A[row,:K], W[:,n]) + b[n] ), 8 rows per block,
// up to 3 segments per launch (block ranges). 256 threads == output cols.
// transOut: write C[n*PN_ + row] (K^T / B^T production).
// ---------------------------------------------------------------------------
struct GSeg {
  const float* A; const float* W; const float* bias; float* C;
  int K; int act; int transOut;
};
struct GArgs { GSeg s[3]; int b0, b1; };

__global__ __launch_bounds__(256) void gemm8(GArgs ga)
{
  extern __shared__ float sA[];   // 8 * K floats
  int bid = blockIdx.x;
  int si = (bid < ga.b0) ? 0 : (bid < ga.b1 ? 1 : 2);
  int base = (si == 0) ? 0 : ((si == 1) ? ga.b0 : ga.b1);
  GSeg sg = ga.s[si];
  int row0 = (bid - base) * 8;
  int K = sg.K;
  int t = threadIdx.x;
  for (int idx = t; idx < 8 * K; idx += 256) {
    int r = idx / K, k = idx - r * K;
    sA[idx] = sg.A[(size_t)(row0 + r) * K + k];
  }
  __syncthreads();
  float acc[8];
  float bv = sg.bias ? sg.bias[t] : 0.f;
  #pragma unroll
  for (int r = 0; r < 8; r++) acc[r] = bv;
  for (int k = 0; k < K; k++) {
    float w = sg.W[(size_t)k * DN_ + t];
    #pragma unroll
    for (int r = 0; r < 8; r++) acc[r] = fmaf(sA[r * K + k], w, acc[r]);
  }
  #pragma unroll
  for (int r = 0; r < 8; r++) {
    float v = acc[r];
    if (sg.act == 1) v = fast_silu(v);
    if (sg.transOut) sg.C[(size_t)t * PN_ + row0 + r] = v;
    else             sg.C[(size_t)(row0 + r) * DN_ + t] = v;
  }
}

// ---------------------------------------------------------------------------
// rbf transpose: rbfT[k][idx] = rbf[idx][k].  256 idx per block, LDS staging.
// grid = LP_/256 = 1024 blocks.
// ---------------------------------------------------------------------------
__global__ __launch_bounds__(256) void rbf_transpose(
    const float* __restrict__ rbf, float* __restrict__ rbfT)
{
  __shared__ float ld[256][RBF_N + 1];   // stride 51 (odd) -> conflict-free
  int t = threadIdx.x;
  size_t base = (size_t)blockIdx.x << 8;
  const float* src = rbf + base * RBF_N;
  // read 256*50 floats flat (coalesced across row boundaries)
  for (int i = 0; i < RBF_N; i++) {
    int fl = i * 256 + t;
    int row = fl / RBF_N, col = fl - row * RBF_N;
    ld[row][col] = src[fl];
  }
  __syncthreads();
  for (int k = 0; k < RBF_N; k++)
    rbfT[(size_t)k * LP_ + base + t] = ld[t][k];
}

// ---------------------------------------------------------------------------
// scores + rbf bias + softmax over P, all 4 heads per block. grid = L blocks.
// Kt: [DN_][PN_]. rbfT: [RBF_N][LP_]. attn layout [l][h][p].
// amean (nullable): attn_out[l*P+p] = mean_h attn
// ---------------------------------------------------------------------------
__global__ __launch_bounds__(256) void scores_softmax_l(
    const float* __restrict__ Q, const float* __restrict__ Kt,
    const float* __restrict__ rbfT, const float* __restrict__ rw,
    const float* __restrict__ rb, float* __restrict__ attn,
    float* __restrict__ amean)
{
  int l = blockIdx.x, t = threadIdx.x, lane = t & 63, wv = t >> 6;
  __shared__ float qs[DN_];
  __shared__ float rws[NH_][RBF_N];
  __shared__ float redm[16], reds[16];
  qs[t] = Q[(size_t)l * DN_ + t];
  if (t < RBF_N * NH_) rws[t & 3][t >> 2] = rw[t];   // rw[k*NH+h]
  __syncthreads();

  float sc[NH_][4];
  for (int i = 0; i < 4; i++) {
    int p = t + (i << 8);
    size_t idx = ((size_t)l << 10) + p;
    float s2[NH_] = {0.f, 0.f, 0.f, 0.f};
    #pragma unroll 10
    for (int k = 0; k < RBF_N; k++) {
      float rv = rbfT[(size_t)k * LP_ + idx];   // coalesced
      s2[0] = fmaf(rv, rws[0][k], s2[0]);
      s2[1] = fmaf(rv, rws[1][k], s2[1]);
      s2[2] = fmaf(rv, rws[2][k], s2[2]);
      s2[3] = fmaf(rv, rws[3][k], s2[3]);
    }
    #pragma unroll
    for (int h = 0; h < NH_; h++) {
      const float* kp = Kt + ((size_t)(h << 6) << 10) + p;
      float a = 0.f;
      #pragma unroll 8
      for (int d = 0; d < HD_; d++) a = fmaf(qs[(h << 6) + d], kp[(size_t)d << 10], a);
      sc[h][i] = a * 0.125f + s2[h] + rb[h];
    }
  }

  float mh[NH_];
  #pragma unroll
  for (int h = 0; h < NH_; h++) {
    float m = fmaxf(fmaxf(sc[h][0], sc[h][1]), fmaxf(sc[h][2], sc[h][3]));
    for (int o = 32; o > 0; o >>= 1) m = fmaxf(m, __shfl_xor(m, o));
    if (lane == 0) redm[h * 4 + wv] = m;
  }
  __syncthreads();
  #pragma unroll
  for (int h = 0; h < NH_; h++)
    mh[h] = fmaxf(fmaxf(redm[h * 4 + 0], redm[h * 4 + 1]),
                  fmaxf(redm[h * 4 + 2], redm[h * 4 + 3]));

  float e[NH_][4], inv[NH_];
  #pragma unroll
  for (int h = 0; h < NH_; h++) {
    float s = 0.f;
    #pragma unroll
    for (int i = 0; i < 4; i++) { e[h][i] = __expf(sc[h][i] - mh[h]); s += e[h][i]; }
    for (int o = 32; o > 0; o >>= 1) s += __shfl_xor(s, o);
    if (lane == 0) reds[h * 4 + wv] = s;
  }
  __syncthreads();
  #pragma unroll
  for (int h = 0; h < NH_; h++)
    inv[h] = 1.f / (reds[h * 4 + 0] + reds[h * 4 + 1] + reds[h * 4 + 2] + reds[h * 4 + 3]);

  #pragma unroll
  for (int h = 0; h < NH_; h++)
    for (int i = 0; i < 4; i++)
      attn[(((size_t)(l << 2) + h) << 10) + t + (i << 8)] = e[h][i] * inv[h];

  if (amean) {
    for (int i = 0; i < 4; i++) {
      float s = e[0][i] * inv[0] + e[1][i] * inv[1] + e[2][i] * inv[2] + e[3][i] * inv[3];
      amean[((size_t)l << 10) + t + (i << 8)] = s * 0.25f;
    }
  }
}

// ---------------------------------------------------------------------------
// attend + output proj + residual + layernorm, fused. grid = L blocks.
// ---------------------------------------------------------------------------
__global__ __launch_bounds__(256) void attend_proj_ln(
    const float* __restrict__ attn, const float* __restrict__ V,
    const float* __restrict__ ow, const float* __restrict__ ob,
    const float* __restrict__ g, const float* __restrict__ bb,
    float* __restrict__ lig)
{
  int l = blockIdx.x, t = threadIdx.x, lane = t & 63, wv = t >> 6;
  int h = t >> 6, d = t & 63;
  __shared__ float as[DN_];
  __shared__ float red[8];
  const float* aw = attn + (((size_t)(l << 2) + h) << 10);
  const float* Vp = V + (h << 6) + d;
  float acc = 0.f;
  #pragma unroll 8
  for (int p = 0; p < PN_; p++) acc = fmaf(aw[p], Vp[(size_t)p << 8], acc);
  as[t] = acc;
  __syncthreads();
  float acc2 = ob[t];
  #pragma unroll 4
  for (int k = 0; k < DN_; k++) acc2 = fmaf(as[k], ow[(size_t)(k << 8) + t], acc2);
  float x = lig[((size_t)l << 8) + t] + acc2;
  float sm = x;
  for (int o = 32; o > 0; o >>= 1) sm += __shfl_xor(sm, o);
  if (lane == 0) red[wv] = sm;
  __syncthreads();
  float mu = (red[0] + red[1] + red[2] + red[3]) * (1.f / DN_);
  float dx = x - mu;
  float v = dx * dx;
  for (int o = 32; o > 0; o >>= 1) v += __shfl_xor(v, o);
  if (lane == 0) red[4 + wv] = v;
  __syncthreads();
  float var = (red[4] + red[5] + red[6] + red[7]) * (1.f / DN_);
  lig[((size_t)l << 8) + t] = dx * (1.f / sqrtf(var + EPSV)) * g[t] + bb[t];
}

// ---------------------------------------------------------------------------
// gate logits.  grid = L blocks, 128 threads.
// ---------------------------------------------------------------------------
__global__ __launch_bounds__(128) void gate_logits_k(
    const float* __restrict__ lig, const float* __restrict__ w1,
    const float* __restrict__ b1, const float* __restrict__ w2,
    const float* __restrict__ b2, float* __restrict__ glog)
{
  int l = blockIdx.x, n = threadIdx.x, lane = n & 63, wv = n >> 6;
  __shared__ float ls[DN_];
  __shared__ float red[2];
  ls[n] = lig[(size_t)l * DN_ + n];
  ls[n + 128] = lig[(size_t)l * DN_ + n + 128];
  __syncthreads();
  float acc = b1[n];
  #pragma unroll 4
  for (int k = 0; k < DN_; k++) acc = fmaf(ls[k], w1[k * 128 + n], acc);
  float part = tanhf(acc) * w2[n];
  for (int o = 32; o > 0; o >>= 1) part += __shfl_xor(part, o);
  if (lane == 0) red[wv] = part;
  __syncthreads();
  if (n == 0) glog[l] = red[0] + red[1] + b2[0];
}

// ---------------------------------------------------------------------------
// gate softmax + pooled repr + both heads. 1 block, 256 threads.
// ---------------------------------------------------------------------------
__global__ __launch_bounds__(256) void pool_heads(
    const float* __restrict__ lig, const float* __restrict__ glog,
    const float* __restrict__ afw1, const float* __restrict__ afb1,
    const float* __restrict__ afw2, const float* __restrict__ afb2,
    const float* __restrict__ cfw1, const float* __restrict__ cfb1,
    const float* __restrict__ cfw2, const float* __restrict__ cfb2,
    float* __restrict__ out)
{
  __shared__ float wsh[LN_];
  __shared__ float cr[DN_];
  __shared__ float h1s[DN_];
  __shared__ float h2s[128];
  __shared__ float red[8];
  int t = threadIdx.x, lane = t & 63, wv = t >> 6;
  float x = glog[t];
  float m = x;
  for (int o = 32; o > 0; o >>= 1) m = fmaxf(m, __shfl_xor(m, o));
  if (lane == 0) red[wv] = m;
  __syncthreads();
  m = fmaxf(fmaxf(red[0], red[1]), fmaxf(red[2], red[3]));
  float e = __expf(x - m);
  float s = e;
  for (int o = 32; o > 0; o >>= 1) s += __shfl_xor(s, o);
  if (lane == 0) red[4 + wv] = s;
  __syncthreads();
  s = red[4] + red[5] + red[6] + red[7];
  wsh[t] = e / s;
  __syncthreads();
  float acc = 0.f;
  #pragma unroll 4
  for (int l2 = 0; l2 < LN_; l2++) acc = fmaf(wsh[l2], lig[(size_t)l2 * DN_ + t], acc);
  cr[t] = acc;
  __syncthreads();
  float a = afb1[t];
  #pragma unroll 4
  for (int d = 0; d < DN_; d++) a = fmaf(cr[d], afw1[d * DN_ + t], a);
  h1s[t] = fast_silu(a);
  if (t < 128) {
    float c = cfb1[t];
    #pragma unroll 4
    for (int d = 0; d < DN_; d++) c = fmaf(cr[d], cfw1[d * 128 + t], c);
    h2s[t] = fast_silu(c);
  }
  __syncthreads();
  float pp = h1s[t] * afw2[t];
  for (int o = 32; o > 0; o >>= 1) pp += __shfl_xor(pp, o);
  if (lane == 0) red[wv] = pp;
  float cp = (t < 128) ? h2s[t] * cfw2[t] : 0.f;
  for (int o = 32; o > 0; o >>= 1) cp += __shfl_xor(cp, o);
  if (lane == 0) red[4 + wv] = cp;
  __syncthreads();
  if (t == 0) {
    float pkd = red[0] + red[1] + red[2] + red[3] + afb2[0];
    float cl  = red[4] + red[5] + red[6] + red[7] + cfb2[0];
    float conf = fast_sigmoid(cl);
    out[0] = pkd * conf;
    out[1] = pkd;
    out[2] = conf;
  }
}

// ---------------------------------------------------------------------------
// pair head v2: register-blocked GEMM. thread = pair, h[64] accum per d-tile,
// k streamed via rbfT (coalesced), Wr/A/w2 on the scalar (s_load) path.
// grid = LP_/256 = 1024 blocks. No LDS.
// ---------------------------------------------------------------------------
__global__ __launch_bounds__(256, 4) void pair_main2(
    const float* __restrict__ A, const float* __restrict__ BT,
    const float* __restrict__ rbfT, const float* __restrict__ Wr,
    const float* __restrict__ w2, const float* __restrict__ ib2,
    float* __restrict__ imap)
{
  int t = threadIdx.x;
  int bid = blockIdx.x;
  int l = bid >> 2;
  int p = ((bid & 3) << 8) + t;
  size_t idx = ((size_t)l << 10) + p;
  const float* Ar = A + (l << 8);          // wave-uniform -> s_load
  float acc[5];
  #pragma unroll
  for (int o = 0; o < 5; o++) acc[o] = ib2[o];

  for (int dt = 0; dt < 4; dt++) {
    int d0 = dt << 6;
    float h[64];
    #pragma unroll
    for (int j = 0; j < 64; j++)
      h[j] = Ar[d0 + j] + BT[(size_t)(d0 + j) * PN_ + p];   // coalesced

    #pragma unroll 2
    for (int k = 0; k < RBF_N; k++) {
      float rv = rbfT[(size_t)k * LP_ + idx];               // coalesced
      const float* wr = Wr + k * DN_ + d0;                  // uniform -> s_load
      #pragma unroll
      for (int j = 0; j < 64; j++)
        h[j] = fmaf(rv, wr[j], h[j]);
    }

    #pragma unroll
    for (int j = 0; j < 64; j++) {
      float sh = fast_silu(h[j]);
      const float* w2r = w2 + (size_t)(d0 + j) * 5;         // uniform -> s_load
      #pragma unroll
      for (int o = 0; o < 5; o++) acc[o] = fmaf(sh, w2r[o], acc[o]);
    }
  }
  float* op = imap + idx * 5;
  #pragma unroll
  for (int o = 0; o < 5; o++) op[o] = fast_sigmoid(acc[o]);
}

// ---------------------------------------------------------------------------
extern "C" void kernel_launch(void* const* d_in, const int* in_sizes, int n_in,
                              void* d_out, int out_size, void* d_ws, size_t ws_size,
                              hipStream_t stream)
{
  const float* pf    = (const float*)d_in[0];
  const float* lf    = (const float*)d_in[1];
  const float* rbf   = (const float*)d_in[4];
  const float* pe_w1 = (const float*)d_in[5];
  const float* pe_b1 = (const float*)d_in[6];
  const float* pe_w2 = (const float*)d_in[7];
  const float* pe_b2 = (const float*)d_in[8];
  const float* le_w1 = (const float*)d_in[9];
  const float* le_b1 = (const float*)d_in[10];
  const float* le_w2 = (const float*)d_in[11];
  const float* le_b2 = (const float*)d_in[12];
  const float* qw = (const float*)d_in[13];
  const float* qb = (const float*)d_in[14];
  const float* kw = (const float*)d_in[15];
  const float* kb = (const float*)d_in[16];
  const float* vw = (const float*)d_in[17];
  const float* vb = (const float*)d_in[18];
  const float* rw = (const float*)d_in[19];
  const float* rb = (const float*)d_in[20];
  const float* ow = (const float*)d_in[21];
  const float* ob = (const float*)d_in[22];
  const float* ln_g = (const float*)d_in[23];
  const float* ln_b = (const float*)d_in[24];
  const float* pg_w1 = (const float*)d_in[25];
  const float* pg_b1 = (const float*)d_in[26];
  const float* pg_w2 = (const float*)d_in[27];
  const float* pg_b2 = (const float*)d_in[28];
  const float* af_w1 = (const float*)d_in[29];
  const float* af_b1 = (const float*)d_in[30];
  const float* af_w2 = (const float*)d_in[31];
  const float* af_b2 = (const float*)d_in[32];
  const float* cf_w1 = (const float*)d_in[33];
  const float* cf_b1 = (const float*)d_in[34];
  const float* cf_w2 = (const float*)d_in[35];
  const float* cf_b2 = (const float*)d_in[36];
  const float* iw1 = (const float*)d_in[37];
  const float* ib1 = (const float*)d_in[38];
  const float* iw2 = (const float*)d_in[39];
  const float* ib2 = (const float*)d_in[40];

  float* out = (float*)d_out;

  // workspace layout (floats)
  float* w = (float*)d_ws;
  size_t off = 0;
  float* prot_h = w + off; off += (size_t)PN_ * DN_;
  float* lig_h  = w + off; off += (size_t)LN_ * DN_;
  float* ph1    = w + off; off += (size_t)PN_ * DN_;
  float* lh1    = w + off; off += (size_t)LN_ * DN_;
  float* Qb     = w + off; off += (size_t)LN_ * DN_;
  float* Kt     = w + off; off += (size_t)DN_ * PN_;   // K^T; reused as pairBT
  float* Vb     = w + off; off += (size_t)PN_ * DN_;
  float* attn   = w + off; off += (size_t)LN_ * NH_ * PN_;
  float* pairA  = w + off; off += (size_t)LN_ * DN_;
  float* glog   = w + off; off += LN_;
  off = (off + 255) & ~(size_t)255;
  float* rbfT   = w + off; off += (size_t)RBF_N * LP_;  // 52.4 MB

  const int PB = PN_ / 8;   // 128
  const int LB = LN_ / 8;   // 32
  const size_t smax = 8 * DN_ * sizeof(float);

  // rbf transpose (feeds scores + pair head)
  rbf_transpose<<<LP_ / 256, 256, 0, stream>>>(rbf, rbfT);

  // encoder stage 1
  {
    GArgs ga;
    ga.s[0] = { pf, pe_w1, pe_b1, ph1, 20, 1, 0 };
    ga.s[1] = { lf, le_w1, le_b1, lh1, 20, 1, 0 };
    ga.s[2] = ga.s[1];
    ga.b0 = PB; ga.b1 = PB + LB;
    gemm8<<<PB + LB, 256, smax, stream>>>(ga);
  }
  // encoder stage 2
  {
    GArgs ga;
    ga.s[0] = { ph1, pe_w2, pe_b2, prot_h, DN_, 0, 0 };
    ga.s[1] = { lh1, le_w2, le_b2, lig_h, DN_, 0, 0 };
    ga.s[2] = ga.s[1];
    ga.b0 = PB; ga.b1 = PB + LB;
    gemm8<<<PB + LB, 256, smax, stream>>>(ga);
  }

  // cross-attention layers
  for (int i = 0; i < NL_; i++) {
    const size_t wo = (size_t)i * DN_ * DN_;
    {
      GArgs ga;
      ga.s[0] = { lig_h,  qw + wo, qb + i * DN_, Qb, DN_, 0, 0 };
      ga.s[1] = { prot_h, kw + wo, kb + i * DN_, Kt, DN_, 0, 1 };  // K^T
      ga.s[2] = { prot_h, vw + wo, vb + i * DN_, Vb, DN_, 0, 0 };
      ga.b0 = LB; ga.b1 = LB + PB;
      gemm8<<<LB + 2 * PB, 256, smax, stream>>>(ga);
    }
    scores_softmax_l<<<LN_, 256, 0, stream>>>(
        Qb, Kt, rbfT, rw + (size_t)i * RBF_N * NH_, rb + i * NH_, attn,
        (i == NL_ - 1) ? (out + 3 + (size_t)LN_ * PN_ * 5) : nullptr);
    attend_proj_ln<<<LN_, 256, 0, stream>>>(attn, Vb, ow + wo, ob + i * DN_,
                                            ln_g + i * DN_, ln_b + i * DN_, lig_h);
  }

  // gated pooling + heads
  gate_logits_k<<<LN_, 128, 0, stream>>>(lig_h, pg_w1, pg_b1, pg_w2, pg_b2, glog);
  pool_heads<<<1, 256, 0, stream>>>(lig_h, glog, af_w1, af_b1, af_w2, af_b2,
                                    cf_w1, cf_b1, cf_w2, cf_b2, out);

  // pair head precompute: pairA = lig_h@iw1[0:256]+ib1 (rows),
  // pairBT = (prot_h@iw1[256:512])^T via transOut (reuses Kt buffer)
  {
    GArgs ga;
    ga.s[0] = { lig_h,  iw1,                       ib1,     pairA, DN_, 0, 0 };
    ga.s[1] = { prot_h, iw1 + (size_t)DN_ * DN_,   nullptr, Kt,    DN_, 0, 1 };
    ga.s[2] = ga.s[1];
    ga.b0 = LB; ga.b1 = LB + PB;
    gemm8<<<LB + PB, 256, smax, stream>>>(ga);
  }

  // fused pair head v2
  pair_main2<<<LP_ / 256, 256, 0, stream>>>(
      pairA, Kt, rbfT, iw1 + (size_t)2 * DN_ * DN_, iw2, ib2, out + 3);
}